// Round 2
// baseline (333.517 us; speedup 1.0000x reference)
//
#include <hip/hip_runtime.h>
#include <cstdint>
#include <cstddef>

// Problem constants (fixed by reference):
#define NSLOTS 16
#define DIM    256        // SLOT_DIM = FEAT_DIM = K = N of both GEMMs
#define FEAT   4096
#define LDA    264        // Abuf row stride in bf16 elements (+8 pad)

typedef __attribute__((ext_vector_type(8))) short    short8;   // 8 bf16 bit-patterns (4 VGPRs)
typedef __attribute__((ext_vector_type(4))) float    floatx4;  // MFMA accumulator
typedef __attribute__((ext_vector_type(4))) unsigned uintx4;   // 8 packed bf16

// v_cvt_pk_bf16_f32: 2 f32 -> 1 dword of 2 bf16, RNE (no builtin on gfx950).
__device__ __forceinline__ unsigned cvt_pk_bf16(float lo, float hi) {
    unsigned r;
    asm("v_cvt_pk_bf16_f32 %0, %1, %2" : "=v"(r) : "v"(lo), "v"(hi));
    return r;
}

// ---------------------------------------------------------------------------
// Kernel 1: prep = W-swizzle (blocks 0..63) + mask argmax (blocks 64..1087).
// Swizzle order: Ws[((kt*16+et)*64+lane)*8+j] = W[kt*32+(lane>>4)*8+j][et*16+(lane&15)]
// NOTE: because A-frag and B-frag lane maps are symmetric, this same table
// serves as the A-operand of the TRANSPOSED product W^T . h^T (see core).
// ---------------------------------------------------------------------------
__global__ __launch_bounds__(256) void prep_kernel(
        const float* __restrict__ W1, const float* __restrict__ W2,
        const float* __restrict__ mask,
        short* __restrict__ W1s, short* __restrict__ W2s,
        unsigned char* __restrict__ Idx) {
    int bid = blockIdx.x;
    int tid = threadIdx.x;
    if (bid < 64) {
        int t = bid * 256 + tid;                 // 16384 swizzle threads
        int lane = t & 63;
        int nt   = (t >> 6) & 15;
        int kt   = (t >> 10) & 7;
        int m    = t >> 13;
        const float* W  = m ? W2 : W1;
        short*       Ws = m ? W2s : W1s;
        int n  = nt * 16 + (lane & 15);
        int kb = kt * 32 + (lane >> 4) * 8;
        float v[8];
#pragma unroll
        for (int j = 0; j < 8; ++j)
            v[j] = W[(size_t)(kb + j) * DIM + n];
        uintx4 hv;
#pragma unroll
        for (int j = 0; j < 4; ++j)
            hv[j] = cvt_pk_bf16(v[2 * j], v[2 * j + 1]);
        *(uintx4*)(Ws + ((size_t)((kt * 16 + nt) * 64 + lane)) * 8) = hv;
    } else {
        int t = bid - 64;                        // 0..1023, 256 f's each
        int b = t >> 4;
        int f = ((t & 15) << 8) + tid;
        const float* mp = mask + (size_t)b * NSLOTS * FEAT + f;
        float best = mp[0];
        int bi = 0;
#pragma unroll
        for (int s = 1; s < NSLOTS; ++s) {       // strict > keeps FIRST max (jnp.argmax)
            float v = mp[(size_t)s * FEAT];
            if (v > best) { best = v; bi = s; }
        }
        Idx[(size_t)b * FEAT + f] = (unsigned char)bi;
    }
}

// ---------------------------------------------------------------------------
// Swapped-operand MFMA core: computes the TRANSPOSED tile D[e][f] by calling
// mfma(A = W-frag, B = h-frag). Lane maps are symmetric, so the existing
// swizzle table and the existing LDS A-reads serve unchanged; only the
// operand order and epilogue mapping change. Result: each lane's acc quad is
// 4 CONSECUTIVE floats along e -> dwordx4 stores (4x fewer store instrs).
//
// 512 threads = 8 waves. Wave w: e-group (w&3)*64 (4 et tiles),
// f-group (w>>2)*(FT*16) (FT ft tiles). acc[4][FT].
// w0 = preloaded kt=0 W-fragments (issued before the barrier to hide L2 lat).
// ---------------------------------------------------------------------------
template<int FT>
__device__ __forceinline__ void mfma_core_T(const short* Abuf,
                                            const short* __restrict__ Ws,
                                            int tid, const short8 w0[4],
                                            floatx4 acc[4][FT]) {
    int lane = tid & 63;
    int w    = tid >> 6;
    int f_base = (w >> 2) * (FT * 16);
    int eg     = (w & 3) * 4;            // first e-tile index (16-row tiles of e)
    int frow   = lane & 15;
    int fk     = (lane >> 4) * 8;
#pragma unroll
    for (int kt = 0; kt < 8; ++kt) {
        short8 wf[4], hf[FT];
#pragma unroll
        for (int et = 0; et < 4; ++et)
            wf[et] = (kt == 0) ? w0[et]
                   : *(const short8*)(Ws + ((size_t)((kt * 16 + eg + et) * 64 + lane)) * 8);
#pragma unroll
        for (int ft = 0; ft < FT; ++ft)
            hf[ft] = *(const short8*)(Abuf + (f_base + ft * 16 + frow) * LDA + kt * 32 + fk);
#pragma unroll
        for (int et = 0; et < 4; ++et)
#pragma unroll
            for (int ft = 0; ft < FT; ++ft)
                acc[et][ft] = __builtin_amdgcn_mfma_f32_16x16x32_bf16(
                    wf[et], hf[ft], acc[et][ft], 0, 0, 0);
    }
}

__device__ __forceinline__ void preload_w0(const short* __restrict__ Ws,
                                           int tid, short8 w0[4]) {
    int lane = tid & 63;
    int eg   = ((tid >> 6) & 3) * 4;
#pragma unroll
    for (int et = 0; et < 4; ++et)
        w0[et] = *(const short8*)(Ws + ((size_t)((eg + et) * 64 + lane)) * 8);
}

// ---------------------------------------------------------------------------
// Kernel 2: precompute S1 = slots@W1 + b1 (rows 0..1023) and P1 = pos_embed@W1
// (rows 1024..5119), fp32 into workspace. MT=64 -> 80 blocks (2x parallelism
// vs the old 40), FT=2 (acc[4][2] = 32 VGPR). Memory layout of S1P1 unchanged.
// ---------------------------------------------------------------------------
__global__ __launch_bounds__(512, 4) void precompute_kernel(
        const float* __restrict__ slots, const float* __restrict__ pos,
        const float* __restrict__ b1, const short* __restrict__ W1s,
        float* __restrict__ S1P1) {
    __shared__ short Abuf[64 * LDA];
    int tid  = threadIdx.x;
    int row0 = blockIdx.x * 64;          // [0, 5120); 1024 % 64 == 0

    short8 w0[4];
    preload_w0(W1s, tid, w0);            // kt=0 fragments in flight during staging

#pragma unroll
    for (int p = 0; p < 4; ++p) {
        int v   = tid + p * 512;         // 0..2047 -> (row, k-octet)
        int row = v >> 5;
        int k0  = (v & 31) * 8;
        int gr  = row0 + row;
        const float* src = (gr < 1024) ? (slots + (size_t)gr * DIM + k0)
                                       : (pos + (size_t)(gr - 1024) * DIM + k0);
        floatx4 a0 = *(const floatx4*)src;
        floatx4 a1 = *(const floatx4*)(src + 4);
        uintx4 hv;
        hv[0] = cvt_pk_bf16(a0[0], a0[1]);
        hv[1] = cvt_pk_bf16(a0[2], a0[3]);
        hv[2] = cvt_pk_bf16(a1[0], a1[1]);
        hv[3] = cvt_pk_bf16(a1[2], a1[3]);
        *(uintx4*)(Abuf + row * LDA + k0) = hv;
    }
    __syncthreads();

    floatx4 acc[4][2];
#pragma unroll
    for (int et = 0; et < 4; ++et)
#pragma unroll
        for (int ft = 0; ft < 2; ++ft)
            acc[et][ft] = floatx4{0.f, 0.f, 0.f, 0.f};
    mfma_core_T<2>(Abuf, W1s, tid, w0, acc);

    int lane = tid & 63, w = tid >> 6;
    bool isSlots = (row0 < 1024);
#pragma unroll
    for (int et = 0; et < 4; ++et) {
        int e0 = (w & 3) * 64 + et * 16 + (lane >> 4) * 4;
        floatx4 bias = isSlots ? *(const floatx4*)(b1 + e0)
                               : floatx4{0.f, 0.f, 0.f, 0.f};
#pragma unroll
        for (int ft = 0; ft < 2; ++ft) {
            int f = (w >> 2) * 32 + ft * 16 + (lane & 15);
            floatx4 r = acc[et][ft] + bias;
            *(floatx4*)(S1P1 + (size_t)(row0 + f) * DIM + e0) = r;   // x4 store
        }
    }
}

// ---------------------------------------------------------------------------
// Kernel 3: fused main. Per 128-row tile (one b, 128 consecutive f):
//   h = relu(S1[b,Idx[row]] + P1[f]) as bf16 in LDS -> transposed MFMA vs W2s
//   -> +b2 -> nontemporal dwordx4 fp32 stores (keeps Ws/S1P1/P1 L2-resident).
// ---------------------------------------------------------------------------
__global__ __launch_bounds__(512, 4) void fused_main_kernel(
        const float* __restrict__ b2, const float* __restrict__ S1P1,
        const short* __restrict__ W2s, const unsigned char* __restrict__ Idx,
        float* __restrict__ out) {
    __shared__ short Abuf[128 * LDA];
    int tid  = threadIdx.x;
    int row0 = blockIdx.x * 128;         // global output row = b*4096 + f
    int b    = row0 >> 12;

    short8 w0[4];
    preload_w0(W2s, tid, w0);            // kt=0 fragments in flight during staging

    // build h tile: relu(S1[b, idx[row]] + P1[f0+row]) -> bf16 into LDS
    const float* P1 = S1P1 + (size_t)1024 * DIM;
#pragma unroll
    for (int p = 0; p < 8; ++p) {
        int v   = tid + p * 512;
        int row = v >> 5;
        int k0  = (v & 31) * 8;
        int s   = Idx[row0 + row];       // Idx is [b][f] flat == global row index
        const floatx4* s1 = (const floatx4*)(S1P1 + ((size_t)(b * NSLOTS + s)) * DIM + k0);
        const floatx4* p1 = (const floatx4*)(P1 + (size_t)(row0 - (size_t)b * FEAT + row) * DIM + k0);
        floatx4 x0 = s1[0] + p1[0];
        floatx4 x1 = s1[1] + p1[1];
        uintx4 hv;
        hv[0] = cvt_pk_bf16(fmaxf(x0[0], 0.f), fmaxf(x0[1], 0.f));
        hv[1] = cvt_pk_bf16(fmaxf(x0[2], 0.f), fmaxf(x0[3], 0.f));
        hv[2] = cvt_pk_bf16(fmaxf(x1[0], 0.f), fmaxf(x1[1], 0.f));
        hv[3] = cvt_pk_bf16(fmaxf(x1[2], 0.f), fmaxf(x1[3], 0.f));
        *(uintx4*)(Abuf + row * LDA + k0) = hv;
    }
    __syncthreads();

    floatx4 acc[4][4];
#pragma unroll
    for (int et = 0; et < 4; ++et)
#pragma unroll
        for (int ft = 0; ft < 4; ++ft)
            acc[et][ft] = floatx4{0.f, 0.f, 0.f, 0.f};
    mfma_core_T<4>(Abuf, W2s, tid, w0, acc);

    // epilogue: + b2, nontemporal x4 stores (lane quad = 4 consecutive e)
    int lane = tid & 63, w = tid >> 6;
#pragma unroll
    for (int et = 0; et < 4; ++et) {
        int e0 = (w & 3) * 64 + et * 16 + (lane >> 4) * 4;
        floatx4 bias = *(const floatx4*)(b2 + e0);
#pragma unroll
        for (int ft = 0; ft < 4; ++ft) {
            int f = (w >> 2) * 64 + ft * 16 + (lane & 15);
            floatx4 r = acc[et][ft] + bias;
            __builtin_nontemporal_store(
                r, (floatx4*)(out + (size_t)(row0 + f) * DIM + e0));
        }
    }
}

// ---------------------------------------------------------------------------
extern "C" void kernel_launch(void* const* d_in, const int* in_sizes, int n_in,
                              void* d_out, int out_size, void* d_ws, size_t ws_size,
                              hipStream_t stream) {
    const float* slots = (const float*)d_in[0];  // [64,16,256]
    const float* mask  = (const float*)d_in[1];  // [64,16,4096]
    const float* pos   = (const float*)d_in[2];  // [1,4096,256]
    const float* W1    = (const float*)d_in[3];  // [256,256]
    const float* b1    = (const float*)d_in[4];  // [256]
    const float* W2    = (const float*)d_in[5];  // [256,256]
    const float* b2    = (const float*)d_in[6];  // [256]
    float* out = (float*)d_out;                  // [64,4096,256] fp32

    // workspace: S1P1 fp32 [5120*256] (5 MB) | W1s bf16 64K | W2s bf16 64K | Idx u8 256K
    char* ws = (char*)d_ws;
    float* S1P1 = (float*)ws;
    short* W1s  = (short*)(ws + (size_t)5120 * 256 * 4);
    short* W2s  = W1s + 65536;
    unsigned char* Idx = (unsigned char*)(W2s + 65536);

    prep_kernel<<<1088, 256, 0, stream>>>(W1, W2, mask, W1s, W2s, Idx);
    precompute_kernel<<<80, 512, 0, stream>>>(slots, pos, b1, W1s, S1P1);
    fused_main_kernel<<<2048, 512, 0, stream>>>(b2, S1P1, W2s, Idx, out);
}